// Round 5
// baseline (11083.930 us; speedup 1.0000x reference)
//
#include <hip/hip_runtime.h>

// Decoder scan: B=1024, T=128, M=256, P=256, 127 steps.
// R7: wave specialization. 256 blocks x 12 waves (768 thr), 4 batches/block.
// Waves 8-11 = ring waves (1/SIMD): all G1/G2 MFMA, weights global->VGPR
// directly (no LDS staging). Waves 0-7 = score waves (2/SIMD): each lane owns
// one t-row of XW (256 bf16 = 64 AGPR + 64 VGPR), m-reduce scores with
// broadcast ds_read of packed (dW,v) bf16 pairs -> zero shuffles in scores.
// G2 delivery overlaps scores on the same SIMDs. 3 __syncthreads per step.
// R5/R6 evidence: bytes+latency not the wall; DS-pipe (~3.2K ops/step) and
// lockstep phase serialization were.

#define B_SZ 1024
#define T_SZ 128
#define M_SZ 256
#define NSTEP 127

typedef __attribute__((ext_vector_type(8))) short short8;
typedef __attribute__((ext_vector_type(4))) float f32x4;

__device__ __forceinline__ float bf2f_lo(unsigned u) {
  return __builtin_bit_cast(float, u << 16);
}
__device__ __forceinline__ float bf2f_hi(unsigned u) {
  return __builtin_bit_cast(float, u & 0xffff0000u);
}
__device__ __forceinline__ unsigned short f2bf(float f) {
  unsigned u = __builtin_bit_cast(unsigned, f);
  u = (u + 0x7fffu + ((u >> 16) & 1u)) >> 16;  // RNE
  return (unsigned short)u;
}
__device__ __forceinline__ float fexp2(float x) { return __builtin_amdgcn_exp2f(x); }
__device__ __forceinline__ float frcp(float x) { return __builtin_amdgcn_rcpf(x); }
__device__ __forceinline__ float tanh_f(float x) {
  float t = fexp2(x * 2.8853900817779268f);
  return 1.f - 2.f * frcp(t + 1.f);
}
__device__ __forceinline__ float sigm_f(float x) {
  return frcp(1.f + fexp2(x * -1.4426950408889634f));
}
__device__ __forceinline__ short8 as_s8(uint4 u) { return __builtin_bit_cast(short8, u); }

// ---------------- prep: weight bf16 fragment swizzles + bias sum ----------------
__global__ void prep_w(const float* __restrict__ WU_d,
                       const float* __restrict__ W_hh,
                       const float* __restrict__ b_ih,
                       const float* __restrict__ b_hh,
                       unsigned short* __restrict__ W1F,
                       unsigned short* __restrict__ W2F,
                       unsigned short* __restrict__ WxF,
                       float* __restrict__ bsum) {
  int i = blockIdx.x * 256 + threadIdx.x;
  if (i < 131072) {
    int j = i & 7, lane = (i >> 3) & 63, ks = (i >> 9) & 15, mt = i >> 13;
    int r = lane & 15, kg = lane >> 4;
    int k = ks * 32 + kg * 8 + j;
    W1F[i] = f2bf(WU_d[(mt * 16 + r) * 768 + k]);
  } else if (i < 131072 + 262144) {
    int i2 = i - 131072;
    int j = i2 & 7, lane = (i2 >> 3) & 63, ks = (i2 >> 9) & 7, jt = i2 >> 12;
    int r = lane & 15, kg = lane >> 4;
    int k = ks * 32 + kg * 8 + j;
    W2F[i2] = f2bf(W_hh[(jt * 16 + r) * 256 + k]);
  } else if (i < 131072 + 262144 + 65536) {
    int i3 = i - (131072 + 262144);
    int j = i3 & 7, lane = (i3 >> 3) & 63, ks = (i3 >> 9) & 7, mt = i3 >> 12;
    int r = lane & 15, kg = lane >> 4;
    int k = 512 + ks * 32 + kg * 8 + j;
    WxF[i3] = f2bf(WU_d[(mt * 16 + r) * 768 + k]);
  } else if (i < 131072 + 262144 + 65536 + 1024) {
    int i4 = i - (131072 + 262144 + 65536);
    bsum[i4] = b_ih[i4] + b_hh[i4];
  }
}

// ---------------- prep: XW = X @ WU_dx^T (bf16) and XWl[b][t] = Wl[1:].X[b][t] ----------------
__global__ __launch_bounds__(256, 1) void prep_xw(
    const float* __restrict__ X,            // (T=128, B=1024, M=256) fp32
    const unsigned short* __restrict__ WxF,
    const float* __restrict__ Wl,           // 257
    unsigned short* __restrict__ XW,        // (B,T,M) bf16
    float* __restrict__ XWl) {              // (B,T) fp32
  __shared__ __align__(16) unsigned short XL[128 * 256];
  const int b = blockIdx.x, tid = threadIdx.x;
  for (int i = tid; i < 128 * 256; i += 256) {
    int t = i >> 8, k = i & 255;
    XL[i] = f2bf(X[(size_t)t * 262144 + (size_t)b * 256 + k]);
  }
  __syncthreads();
  const int wave = tid >> 6, lane = tid & 63, r = lane & 15, kg = lane >> 4;
  for (int tt = 0; tt < 8; ++tt) {
    uint4 a[8];
#pragma unroll
    for (int ks = 0; ks < 8; ++ks)
      a[ks] = *(const uint4*)&XL[(tt * 16 + r) * 256 + ks * 32 + kg * 8];
#pragma unroll
    for (int mtl = 0; mtl < 4; ++mtl) {
      const int mt = wave * 4 + mtl;
      f32x4 acc = {0.f, 0.f, 0.f, 0.f};
#pragma unroll
      for (int ks = 0; ks < 8; ++ks) {
        uint4 braw = *(const uint4*)(WxF + ((size_t)(mt * 8 + ks) * 64 + lane) * 8);
        acc = __builtin_amdgcn_mfma_f32_16x16x32_bf16(as_s8(a[ks]), as_s8(braw), acc, 0, 0, 0);
      }
#pragma unroll
      for (int rr = 0; rr < 4; ++rr) {
        int trow = tt * 16 + kg * 4 + rr;
        XW[(size_t)b * 32768 + trow * 256 + mt * 16 + r] = f2bf(acc[rr]);
      }
    }
  }
  float wl4[4];
#pragma unroll
  for (int j = 0; j < 4; ++j) wl4[j] = Wl[1 + lane * 4 + j];
  for (int t = wave * 32; t < wave * 32 + 32; ++t) {
    uint2 q = *(const uint2*)&XL[t * 256 + lane * 4];
    float s = wl4[0] * bf2f_lo(q.x) + wl4[1] * bf2f_hi(q.x) +
              wl4[2] * bf2f_lo(q.y) + wl4[3] * bf2f_hi(q.y);
#pragma unroll
    for (int off = 1; off < 64; off <<= 1) s += __shfl_xor(s, off, 64);
    if (lane == 0) XWl[b * 128 + t] = s;
  }
}

// ---- AGPR pin helpers: first half of the lane's XW t-row (m 0..127) ----
#define XA_DECL(n) unsigned xa##n##_0, xa##n##_1, xa##n##_2, xa##n##_3;

#define XA_LOAD(n)                                                        \
  {                                                                       \
    uint4 t_ = *(const uint4*)(p_ + (n) * 8);                             \
    asm("v_accvgpr_write_b32 %0, %1" : "=a"(xa##n##_0) : "v"(t_.x));      \
    asm("v_accvgpr_write_b32 %0, %1" : "=a"(xa##n##_1) : "v"(t_.y));      \
    asm("v_accvgpr_write_b32 %0, %1" : "=a"(xa##n##_2) : "v"(t_.z));      \
    asm("v_accvgpr_write_b32 %0, %1" : "=a"(xa##n##_3) : "v"(t_.w));      \
  }

// 8 m-values: q0..q3 = 4 dwords of XW bf16 pairs; dv = packed (dW lo, v hi)
#define SC8(q0, q1, q2, q3, mb)                                           \
  {                                                                       \
    uint4 dv0 = *(const uint4*)&dvL[bw][(mb)];                            \
    uint4 dv1 = *(const uint4*)&dvL[bw][(mb) + 4];                        \
    s0 += bf2f_hi(dv0.x) * tanh_f(bf2f_lo(dv0.x) + bf2f_lo(q0));          \
    s1 += bf2f_hi(dv0.y) * tanh_f(bf2f_lo(dv0.y) + bf2f_hi(q0));          \
    s2 += bf2f_hi(dv0.z) * tanh_f(bf2f_lo(dv0.z) + bf2f_lo(q1));          \
    s3 += bf2f_hi(dv0.w) * tanh_f(bf2f_lo(dv0.w) + bf2f_hi(q1));          \
    s0 += bf2f_hi(dv1.x) * tanh_f(bf2f_lo(dv1.x) + bf2f_lo(q2));          \
    s1 += bf2f_hi(dv1.y) * tanh_f(bf2f_lo(dv1.y) + bf2f_hi(q2));          \
    s2 += bf2f_hi(dv1.z) * tanh_f(bf2f_lo(dv1.z) + bf2f_lo(q3));          \
    s3 += bf2f_hi(dv1.w) * tanh_f(bf2f_lo(dv1.w) + bf2f_hi(q3));          \
  }

#define XA_USE(n, mb)                                                     \
  {                                                                       \
    unsigned q0, q1, q2, q3;                                              \
    asm("v_accvgpr_read_b32 %0, %1" : "=v"(q0) : "a"(xa##n##_0));         \
    asm("v_accvgpr_read_b32 %0, %1" : "=v"(q1) : "a"(xa##n##_1));         \
    asm("v_accvgpr_read_b32 %0, %1" : "=v"(q2) : "a"(xa##n##_2));         \
    asm("v_accvgpr_read_b32 %0, %1" : "=v"(q3) : "a"(xa##n##_3));         \
    SC8(q0, q1, q2, q3, mb)                                               \
  }

#define XV_USE(n, mb)                                                     \
  {                                                                       \
    uint4 q_ = xwv[n];                                                    \
    SC8(q_.x, q_.y, q_.z, q_.w, mb)                                       \
  }

#define MFMA_BF16(a, b, c) __builtin_amdgcn_mfma_f32_16x16x32_bf16(as_s8(a), as_s8(b), c, 0, 0, 0)

// ---------------- main scan: 256 blocks x 768 thr = 12 waves (8 score + 4 ring) ----------------
__global__ __launch_bounds__(768, 3) void scan_k(
    const float* __restrict__ Yg,            // (1024,127,1)
    const float* __restrict__ X,             // (T,B,M) fp32 (final ctx only)
    const unsigned short* __restrict__ XW,   // (B,T,M) bf16
    const float* __restrict__ XWl,           // (B,T) fp32
    const unsigned short* __restrict__ W1F,
    const unsigned short* __restrict__ W2F,
    const float* __restrict__ bsum,          // 1024
    const float* __restrict__ v_d,           // 256
    const float* __restrict__ Wl,            // 257
    const float* __restrict__ W_ih,          // 1024
    const float* __restrict__ Wb_w,          // 256x512
    const float* __restrict__ Wb_b,          // 256
    const float* __restrict__ vb_w,          // 256
    const float* __restrict__ vb_b,          // 1
    float* __restrict__ outp) {              // 1024
  __shared__ __align__(16) unsigned short hcbf[4][520];  // [b][0:256)=h, [256:512)=c (bf16)
  __shared__ __align__(16) unsigned dvL[4][256];         // packed (dW bf16 lo, v bf16 hi)
  __shared__ __align__(16) float gL[4][1024];
  __shared__ float lL[4][128];
  __shared__ float betaL[4][128];
  __shared__ float yL[4][128];
  __shared__ float ihL[1024];
  __shared__ float bsL[1024];
  __shared__ __align__(16) float ctxW[4][2][256];
  __shared__ float ctxL[4][256];

  const int tid = threadIdx.x;
  const int wave = tid >> 6;       // 0..11
  const int lane = tid & 63;
  const int r = lane & 15;
  const int kg = lane >> 4;
  const int b0 = blockIdx.x * 4;

  // score-wave ids (waves 0..7): batch bw, t-half th, own t, LSTM p pair
  const int bw = wave >> 1;
  const int th = wave & 1;
  const int t = th * 64 + lane;
  const int p0 = th * 128 + lane;
  const int p1 = p0 + 64;
  // ring-wave id (waves 8..11)
  const int rw = wave - 8;

  // init LDS
  for (int i = tid; i < 4 * 520; i += 768) (&hcbf[0][0])[i] = 0;
  for (int i = tid; i < 1024; i += 768) { ihL[i] = W_ih[i]; bsL[i] = bsum[i]; }
  if (tid < 512) {
    int b = tid >> 7, s = tid & 127;
    yL[b][s] = (s < NSTEP) ? Yg[(size_t)(b0 + b) * NSTEP + s] : 0.f;
  }

  // score-wave persistent state: XW t-row in 64 AGPR + 64 VGPR
  XA_DECL(0) XA_DECL(1) XA_DECL(2) XA_DECL(3)
  XA_DECL(4) XA_DECL(5) XA_DECL(6) XA_DECL(7)
  XA_DECL(8) XA_DECL(9) XA_DECL(10) XA_DECL(11)
  XA_DECL(12) XA_DECL(13) XA_DECL(14) XA_DECL(15)
  uint4 xwv[16];
  float xwl0 = 0.f, xwl1 = 0.f;
  float c0 = 0.f, c1 = 0.f, sc = 0.f;
  const float wl0 = Wl[0];
  if (wave < 8) {
    const unsigned short* p_ = XW + (size_t)(b0 + bw) * 32768 + (size_t)t * 256;
    XA_LOAD(0) XA_LOAD(1) XA_LOAD(2) XA_LOAD(3)
    XA_LOAD(4) XA_LOAD(5) XA_LOAD(6) XA_LOAD(7)
    XA_LOAD(8) XA_LOAD(9) XA_LOAD(10) XA_LOAD(11)
    XA_LOAD(12) XA_LOAD(13) XA_LOAD(14) XA_LOAD(15)
#pragma unroll
    for (int n = 0; n < 16; ++n) xwv[n] = *(const uint4*)(p_ + 128 + n * 8);
    xwl0 = XWl[(size_t)(b0 + bw) * 128 + t];
    xwl1 = XWl[(size_t)(b0 + bw) * 128 + (th ^ 1) * 64 + lane];
  }
  // ring-wave preload: v packed to hi-bf16 for the 4 owned mt tiles
  unsigned vpk[4] = {0, 0, 0, 0};
  if (wave >= 8) {
#pragma unroll
    for (int i = 0; i < 4; ++i)
      vpk[i] = (unsigned)f2bf(v_d[(rw * 4 + i) * 16 + r]) << 16;
  }

  __syncthreads();

  for (int step = 0; step < NSTEP; ++step) {
    // ---- Phase 1: ring waves: G1 dW = d @ W1^T (4 mt tiles), write dvL ----
    if (wave >= 8) {
      const unsigned short* w1p = W1F + (size_t)(rw * 4) * 8192 + (size_t)lane * 8;
      f32x4 a0 = {0.f, 0.f, 0.f, 0.f}, a1 = a0, a2 = a0, a3 = a0;
#pragma unroll
      for (int ks = 0; ks < 16; ++ks) {
        uint4 av = *(const uint4*)&hcbf[r & 3][ks * 32 + kg * 8];
        uint4 q0 = *(const uint4*)(w1p + 0 * 8192 + ks * 512);
        uint4 q1 = *(const uint4*)(w1p + 1 * 8192 + ks * 512);
        uint4 q2 = *(const uint4*)(w1p + 2 * 8192 + ks * 512);
        uint4 q3 = *(const uint4*)(w1p + 3 * 8192 + ks * 512);
        a0 = MFMA_BF16(av, q0, a0);
        a1 = MFMA_BF16(av, q1, a1);
        a2 = MFMA_BF16(av, q2, a2);
        a3 = MFMA_BF16(av, q3, a3);
      }
      if (kg == 0) {
        const int mB = (rw * 4) * 16 + r;
#pragma unroll
        for (int rr = 0; rr < 4; ++rr) {
          dvL[rr][mB] = (unsigned)f2bf(a0[rr]) | vpk[0];
          dvL[rr][mB + 16] = (unsigned)f2bf(a1[rr]) | vpk[1];
          dvL[rr][mB + 32] = (unsigned)f2bf(a2[rr]) | vpk[2];
          dvL[rr][mB + 48] = (unsigned)f2bf(a3[rr]) | vpk[3];
        }
      }
    }
    __syncthreads();

    // ---- Phase 2: score waves m-reduce scores || ring waves G2 gates ----
    if (wave < 8) {
      float s0 = 0.f, s1 = 0.f, s2 = 0.f, s3 = 0.f;
      XA_USE(0, 0)  XA_USE(1, 8)  XA_USE(2, 16)  XA_USE(3, 24)
      XA_USE(4, 32) XA_USE(5, 40) XA_USE(6, 48)  XA_USE(7, 56)
      XA_USE(8, 64) XA_USE(9, 72) XA_USE(10, 80) XA_USE(11, 88)
      XA_USE(12, 96) XA_USE(13, 104) XA_USE(14, 112) XA_USE(15, 120)
      XV_USE(0, 128) XV_USE(1, 136) XV_USE(2, 144) XV_USE(3, 152)
      XV_USE(4, 160) XV_USE(5, 168) XV_USE(6, 176) XV_USE(7, 184)
      XV_USE(8, 192) XV_USE(9, 200) XV_USE(10, 208) XV_USE(11, 216)
      XV_USE(12, 224) XV_USE(13, 232) XV_USE(14, 240) XV_USE(15, 248)
      sc = (s0 + s1) + (s2 + s3);
      lL[bw][t] = sc;
    } else {
      const unsigned short* w2p = W2F + (size_t)(rw * 16) * 4096 + (size_t)lane * 8;
#pragma unroll
      for (int jtg = 0; jtg < 4; ++jtg) {
        f32x4 g0 = {0.f, 0.f, 0.f, 0.f}, g1 = g0, g2 = g0, g3 = g0;
#pragma unroll
        for (int ks = 0; ks < 8; ++ks) {
          uint4 av = *(const uint4*)&hcbf[r & 3][ks * 32 + kg * 8];
          uint4 q0 = *(const uint4*)(w2p + (jtg * 4 + 0) * 4096 + ks * 512);
          uint4 q1 = *(const uint4*)(w2p + (jtg * 4 + 1) * 4096 + ks * 512);
          uint4 q2 = *(const uint4*)(w2p + (jtg * 4 + 2) * 4096 + ks * 512);
          uint4 q3 = *(const uint4*)(w2p + (jtg * 4 + 3) * 4096 + ks * 512);
          g0 = MFMA_BF16(av, q0, g0);
          g1 = MFMA_BF16(av, q1, g1);
          g2 = MFMA_BF16(av, q2, g2);
          g3 = MFMA_BF16(av, q3, g3);
        }
        if (kg == 0) {
          const int jb = (rw * 16 + jtg * 4) * 16 + r;
#pragma unroll
          for (int rr = 0; rr < 4; ++rr) {
            gL[rr][jb] = g0[rr];
            gL[rr][jb + 16] = g1[rr];
            gL[rr][jb + 32] = g2[rr];
            gL[rr][jb + 48] = g3[rr];
          }
        }
      }
    }
    __syncthreads();

    // ---- Phase 3: score waves: softmax + y_tilde + LSTM; ring waves idle ----
    if (wave < 8) {
      float l0 = sc, l1 = lL[bw][(th ^ 1) * 64 + lane];
      float mx = fmaxf(l0, l1);
#pragma unroll
      for (int off = 1; off < 64; off <<= 1) mx = fmaxf(mx, __shfl_xor(mx, off, 64));
      float e0 = fexp2((l0 - mx) * 1.4426950408889634f);
      float e1 = fexp2((l1 - mx) * 1.4426950408889634f);
      float sm = e0 + e1;
      float yt = e0 * xwl0 + e1 * xwl1;
#pragma unroll
      for (int off = 1; off < 64; off <<= 1) {
        sm += __shfl_xor(sm, off, 64);
        yt += __shfl_xor(yt, off, 64);
      }
      float inv = frcp(sm);
      if (step == NSTEP - 1) betaL[bw][t] = e0 * inv;
      yt = yt * inv + wl0 * yL[bw][step];
      // LSTM for p0
      float ig = gL[bw][p0] + yt * ihL[p0] + bsL[p0];
      float fg = gL[bw][256 + p0] + yt * ihL[256 + p0] + bsL[256 + p0];
      float gg = gL[bw][512 + p0] + yt * ihL[512 + p0] + bsL[512 + p0];
      float og = gL[bw][768 + p0] + yt * ihL[768 + p0] + bsL[768 + p0];
      float cn = sigm_f(fg) * c0 + sigm_f(ig) * tanh_f(gg);
      float hn = sigm_f(og) * tanh_f(cn);
      c0 = cn;
      hcbf[bw][p0] = f2bf(hn);
      hcbf[bw][256 + p0] = f2bf(cn);
      // LSTM for p1
      ig = gL[bw][p1] + yt * ihL[p1] + bsL[p1];
      fg = gL[bw][256 + p1] + yt * ihL[256 + p1] + bsL[256 + p1];
      gg = gL[bw][512 + p1] + yt * ihL[512 + p1] + bsL[512 + p1];
      og = gL[bw][768 + p1] + yt * ihL[768 + p1] + bsL[768 + p1];
      cn = sigm_f(fg) * c1 + sigm_f(ig) * tanh_f(gg);
      hn = sigm_f(og) * tanh_f(cn);
      c1 = cn;
      hcbf[bw][p1] = f2bf(hn);
      hcbf[bw][256 + p1] = f2bf(cn);
    }
    __syncthreads();
  }

  // ---- epilogue: ctx from final beta, then output head ----
  if (wave < 8) {
    const int m4 = lane * 4;
    f32x4 c4 = {0.f, 0.f, 0.f, 0.f};
    for (int tt = th * 64; tt < th * 64 + 64; ++tt) {
      float bta = betaL[bw][tt];
      f32x4 x4 = *(const f32x4*)&X[(size_t)tt * 262144 + (size_t)(b0 + bw) * 256 + m4];
      c4.x += bta * x4.x;
      c4.y += bta * x4.y;
      c4.z += bta * x4.z;
      c4.w += bta * x4.w;
    }
    *(f32x4*)&ctxW[bw][th][m4] = c4;
  }
  __syncthreads();
  for (int i = tid; i < 1024; i += 768)
    ctxL[i >> 8][i & 255] = ctxW[i >> 8][0][i & 255] + ctxW[i >> 8][1][i & 255];
  __syncthreads();

  if (wave < 4) {
    const int m4 = lane * 4;
    float h0 = 0.f, h1 = 0.f, h2 = 0.f, h3 = 0.f;
    for (int q = 0; q < 512; ++q) {
      float hcq = (q < 256) ? bf2f_lo((unsigned)hcbf[wave][q]) : ctxL[wave][q - 256];
      const float* wb = Wb_w + (size_t)m4 * 512 + q;
      h0 += hcq * wb[0];
      h1 += hcq * wb[512];
      h2 += hcq * wb[1024];
      h3 += hcq * wb[1536];
    }
    float o = (h0 + Wb_b[m4]) * vb_w[m4] + (h1 + Wb_b[m4 + 1]) * vb_w[m4 + 1] +
              (h2 + Wb_b[m4 + 2]) * vb_w[m4 + 2] + (h3 + Wb_b[m4 + 3]) * vb_w[m4 + 3];
#pragma unroll
    for (int off = 1; off < 64; off <<= 1) o += __shfl_xor(o, off, 64);
    if (lane == 0) outp[b0 + wave] = o + vb_b[0];
  }
}

extern "C" void kernel_launch(void* const* d_in, const int* in_sizes, int n_in,
                              void* d_out, int out_size, void* d_ws, size_t ws_size,
                              hipStream_t stream) {
  const float* Y = (const float*)d_in[0];
  const float* X = (const float*)d_in[1];
  const float* WU_d = (const float*)d_in[2];
  const float* v_d = (const float*)d_in[3];
  const float* Wl = (const float*)d_in[4];
  const float* W_ih = (const float*)d_in[5];
  const float* W_hh = (const float*)d_in[6];
  const float* b_ih = (const float*)d_in[7];
  const float* b_hh = (const float*)d_in[8];
  const float* Wb_w = (const float*)d_in[9];
  const float* Wb_b = (const float*)d_in[10];
  const float* vb_w = (const float*)d_in[11];
  const float* vb_b = (const float*)d_in[12];

  char* ws = (char*)d_ws;
  unsigned short* XW = (unsigned short*)(ws + 0);            // 64 MB
  float* XWl = (float*)(ws + 67108864);                      // 512 KB
  unsigned short* W1F = (unsigned short*)(ws + 67633152);    // 256 KB
  unsigned short* W2F = (unsigned short*)(ws + 67895296);    // 512 KB
  unsigned short* WxF = (unsigned short*)(ws + 68419584);    // 128 KB
  float* bsum = (float*)(ws + 68550656);                     // 4 KB

  prep_w<<<1796, 256, 0, stream>>>(WU_d, W_hh, b_ih, b_hh, W1F, W2F, WxF, bsum);
  prep_xw<<<1024, 256, 0, stream>>>(X, WxF, Wl, XW, XWl);
  scan_k<<<256, 768, 0, stream>>>(Y, X, XW, XWl, W1F, W2F, bsum, v_d, Wl, W_ih,
                                  Wb_w, Wb_b, vb_w, vb_b, (float*)d_out);
}

// Round 6
// 4987.558 us; speedup vs baseline: 2.2223x; 2.2223x over previous
//
#include <hip/hip_runtime.h>

// Decoder scan: B=1024, T=128, M=256, P=256, 127 steps.
// R8 = R5 skeleton (best: 5327us; 16 waves, 4 batches/block, AGPR XW tile,
// 3-pane global_load_lds weight ring) + three cuts:
//  1) transposed scores: lane owns one t (2 lanes/t, 128 m each); XW row in
//     64 asm-pinned AGPRs; dW via broadcast ds_read_b128 of bf16 (dW|v)
//     packs. 80 serial shfl/wave -> 1.
//  2) G1+G2 fused into one ring phase (both read only h,c). 24 chunks.
//  3) softmax computed redundantly by all waves, fused with LSTM; no
//     max-subtract (|l| <= sum|v| ~ 11, exp2 safe). 4 barriers -> 3.
// R3/R7 lesson: plain-array register tiles spill; ONLY inline-asm AGPR holds.

#define B_SZ 1024
#define T_SZ 128
#define M_SZ 256
#define NSTEP 127

typedef __attribute__((ext_vector_type(8))) short short8;
typedef __attribute__((ext_vector_type(4))) float f32x4;

__device__ __forceinline__ float bf2f_lo(unsigned u) {
  return __builtin_bit_cast(float, u << 16);
}
__device__ __forceinline__ float bf2f_hi(unsigned u) {
  return __builtin_bit_cast(float, u & 0xffff0000u);
}
__device__ __forceinline__ unsigned short f2bf(float f) {
  unsigned u = __builtin_bit_cast(unsigned, f);
  u = (u + 0x7fffu + ((u >> 16) & 1u)) >> 16;  // RNE
  return (unsigned short)u;
}
__device__ __forceinline__ float fexp2(float x) { return __builtin_amdgcn_exp2f(x); }
__device__ __forceinline__ float frcp(float x) { return __builtin_amdgcn_rcpf(x); }
__device__ __forceinline__ float tanh_f(float x) {
  float t = fexp2(x * 2.8853900817779268f);
  return 1.f - 2.f * frcp(t + 1.f);
}
__device__ __forceinline__ float sigm_f(float x) {
  return frcp(1.f + fexp2(x * -1.4426950408889634f));
}
__device__ __forceinline__ short8 as_s8(uint4 u) { return __builtin_bit_cast(short8, u); }

// ---------------- prep: weight bf16 fragment swizzles + bias sum ----------------
__global__ void prep_w(const float* __restrict__ WU_d,
                       const float* __restrict__ W_hh,
                       const float* __restrict__ b_ih,
                       const float* __restrict__ b_hh,
                       unsigned short* __restrict__ W1F,
                       unsigned short* __restrict__ W2F,
                       unsigned short* __restrict__ WxF,
                       float* __restrict__ bsum) {
  int i = blockIdx.x * 256 + threadIdx.x;
  if (i < 131072) {
    int j = i & 7, lane = (i >> 3) & 63, ks = (i >> 9) & 15, mt = i >> 13;
    int r = lane & 15, kg = lane >> 4;
    int k = ks * 32 + kg * 8 + j;
    W1F[i] = f2bf(WU_d[(mt * 16 + r) * 768 + k]);
  } else if (i < 131072 + 262144) {
    int i2 = i - 131072;
    int j = i2 & 7, lane = (i2 >> 3) & 63, ks = (i2 >> 9) & 7, jt = i2 >> 12;
    int r = lane & 15, kg = lane >> 4;
    int k = ks * 32 + kg * 8 + j;
    W2F[i2] = f2bf(W_hh[(jt * 16 + r) * 256 + k]);
  } else if (i < 131072 + 262144 + 65536) {
    int i3 = i - (131072 + 262144);
    int j = i3 & 7, lane = (i3 >> 3) & 63, ks = (i3 >> 9) & 7, mt = i3 >> 12;
    int r = lane & 15, kg = lane >> 4;
    int k = 512 + ks * 32 + kg * 8 + j;
    WxF[i3] = f2bf(WU_d[(mt * 16 + r) * 768 + k]);
  } else if (i < 131072 + 262144 + 65536 + 1024) {
    int i4 = i - (131072 + 262144 + 65536);
    bsum[i4] = b_ih[i4] + b_hh[i4];
  }
}

// ---------------- prep: XW = X @ WU_dx^T (bf16) and XWl[b][t] = Wl[1:].X[b][t] ----------------
__global__ __launch_bounds__(256, 1) void prep_xw(
    const float* __restrict__ X,            // (T=128, B=1024, M=256) fp32
    const unsigned short* __restrict__ WxF,
    const float* __restrict__ Wl,           // 257
    unsigned short* __restrict__ XW,        // (B,T,M) bf16
    float* __restrict__ XWl) {              // (B,T) fp32
  __shared__ __align__(16) unsigned short XL[128 * 256];
  const int b = blockIdx.x, tid = threadIdx.x;
  for (int i = tid; i < 128 * 256; i += 256) {
    int t = i >> 8, k = i & 255;
    XL[i] = f2bf(X[(size_t)t * 262144 + (size_t)b * 256 + k]);
  }
  __syncthreads();
  const int wave = tid >> 6, lane = tid & 63, r = lane & 15, kg = lane >> 4;
  for (int tt = 0; tt < 8; ++tt) {
    uint4 a[8];
#pragma unroll
    for (int ks = 0; ks < 8; ++ks)
      a[ks] = *(const uint4*)&XL[(tt * 16 + r) * 256 + ks * 32 + kg * 8];
#pragma unroll
    for (int mtl = 0; mtl < 4; ++mtl) {
      const int mt = wave * 4 + mtl;
      f32x4 acc = {0.f, 0.f, 0.f, 0.f};
#pragma unroll
      for (int ks = 0; ks < 8; ++ks) {
        uint4 braw = *(const uint4*)(WxF + ((size_t)(mt * 8 + ks) * 64 + lane) * 8);
        acc = __builtin_amdgcn_mfma_f32_16x16x32_bf16(as_s8(a[ks]), as_s8(braw), acc, 0, 0, 0);
      }
#pragma unroll
      for (int rr = 0; rr < 4; ++rr) {
        int trow = tt * 16 + kg * 4 + rr;
        XW[(size_t)b * 32768 + trow * 256 + mt * 16 + r] = f2bf(acc[rr]);
      }
    }
  }
  float wl4[4];
#pragma unroll
  for (int j = 0; j < 4; ++j) wl4[j] = Wl[1 + lane * 4 + j];
  for (int t = wave * 32; t < wave * 32 + 32; ++t) {
    uint2 q = *(const uint2*)&XL[t * 256 + lane * 4];
    float s = wl4[0] * bf2f_lo(q.x) + wl4[1] * bf2f_hi(q.x) +
              wl4[2] * bf2f_lo(q.y) + wl4[3] * bf2f_hi(q.y);
#pragma unroll
    for (int off = 1; off < 64; off <<= 1) s += __shfl_xor(s, off, 64);
    if (lane == 0) XWl[b * 128 + t] = s;
  }
}

// ---- AGPR pin: lane's XW row (t fixed, 128 m) = 64 AGPRs ----
#define XA_DECL(n) unsigned xa##n##_0, xa##n##_1, xa##n##_2, xa##n##_3;

#define XA_LOAD(n)                                                        \
  {                                                                       \
    uint4 t_ = *(const uint4*)(p_ + (n) * 8);                             \
    asm("v_accvgpr_write_b32 %0, %1" : "=a"(xa##n##_0) : "v"(t_.x));      \
    asm("v_accvgpr_write_b32 %0, %1" : "=a"(xa##n##_1) : "v"(t_.y));      \
    asm("v_accvgpr_write_b32 %0, %1" : "=a"(xa##n##_2) : "v"(t_.z));      \
    asm("v_accvgpr_write_b32 %0, %1" : "=a"(xa##n##_3) : "v"(t_.w));      \
  }

// macro n covers this lane's m-slots [n*8, n*8+8): XW from AGPR, (dW|v)
// packed dwords from broadcast LDS (dvp base already includes mh*128).
#define XA_USE(n)                                                            \
  {                                                                          \
    unsigned q0, q1, q2, q3;                                                 \
    asm("v_accvgpr_read_b32 %0, %1" : "=v"(q0) : "a"(xa##n##_0));            \
    asm("v_accvgpr_read_b32 %0, %1" : "=v"(q1) : "a"(xa##n##_1));            \
    asm("v_accvgpr_read_b32 %0, %1" : "=v"(q2) : "a"(xa##n##_2));            \
    asm("v_accvgpr_read_b32 %0, %1" : "=v"(q3) : "a"(xa##n##_3));            \
    uint4 dv0 = dvp[2 * (n)];                                                \
    uint4 dv1 = dvp[2 * (n) + 1];                                            \
    s0 += bf2f_hi(dv0.x) * tanh_f(bf2f_lo(dv0.x) + bf2f_lo(q0));             \
    s1 += bf2f_hi(dv0.y) * tanh_f(bf2f_lo(dv0.y) + bf2f_hi(q0));             \
    s2 += bf2f_hi(dv0.z) * tanh_f(bf2f_lo(dv0.z) + bf2f_lo(q1));             \
    s3 += bf2f_hi(dv0.w) * tanh_f(bf2f_lo(dv0.w) + bf2f_hi(q1));             \
    s0 += bf2f_hi(dv1.x) * tanh_f(bf2f_lo(dv1.x) + bf2f_lo(q2));             \
    s1 += bf2f_hi(dv1.y) * tanh_f(bf2f_lo(dv1.y) + bf2f_hi(q2));             \
    s2 += bf2f_hi(dv1.z) * tanh_f(bf2f_lo(dv1.z) + bf2f_lo(q3));             \
    s3 += bf2f_hi(dv1.w) * tanh_f(bf2f_lo(dv1.w) + bf2f_hi(q3));             \
  }

// In-loop barrier: LDS drained, vmcnt (DMA ring) stays in flight (T4).
#define BARL()                                               \
  do {                                                       \
    asm volatile("s_waitcnt lgkmcnt(0)" ::: "memory");       \
    __builtin_amdgcn_s_barrier();                            \
  } while (0)

// Ring wait: oldest in-flight chunk landed when <=4 loads outstanding.
#define RWAIT()                                              \
  do {                                                       \
    asm volatile("s_waitcnt vmcnt(4)" ::: "memory");         \
    __builtin_amdgcn_sched_barrier(0);                       \
  } while (0)

#define MFMA_BF16(a, b, c) __builtin_amdgcn_mfma_f32_16x16x32_bf16(as_s8(a), as_s8(b), c, 0, 0, 0)

// ---------------- main scan: 256 blocks x 1024 thr = 16 waves = 4 batches ----------------
__global__ __launch_bounds__(1024, 4) void scan_k(
    const float* __restrict__ Yg,            // (1024,127,1)
    const float* __restrict__ X,             // (T,B,M) fp32 (final ctx only)
    const unsigned short* __restrict__ XW,   // (B,T,M) bf16
    const float* __restrict__ XWl,           // (B,T) fp32
    const unsigned short* __restrict__ W1F,
    const unsigned short* __restrict__ W2F,
    const float* __restrict__ bsum,          // 1024
    const float* __restrict__ v_d,           // 256
    const float* __restrict__ Wl,            // 257
    const float* __restrict__ W_ih,          // 1024
    const float* __restrict__ Wb_w,          // 256x512
    const float* __restrict__ Wb_b,          // 256
    const float* __restrict__ vb_w,          // 256
    const float* __restrict__ vb_b,          // 1
    float* __restrict__ outp) {              // 1024
  __shared__ __align__(16) unsigned short hcbf[4][520];  // [b][0:256)=h, [256:512)=c (bf16)
  __shared__ __align__(16) unsigned dvL[4][256];         // packed (dW bf16 lo | v bf16 hi)
  __shared__ __align__(16) float gL[4][1024];
  __shared__ float lL[4][128];
  __shared__ float betaL[4][128];
  __shared__ float yL[4][128];
  // DMA ring: 16 waves x 3 panes x 1024 shorts (2 KB). Reused for ctx after
  // the loop (drained first).
  __shared__ __align__(16) unsigned short ringS[16 * 3 * 1024];

  const int tid = threadIdx.x;
  const int wave = tid >> 6;       // 0..15
  const int lane = tid & 63;
  const int r = lane & 15;
  const int kg = lane >> 4;
  const int b0 = blockIdx.x * 4;
  const int bb = wave >> 2;        // batch of this wave (0..3)
  const int tw = wave & 3;         // t-chunk of this wave (0..3)
  const int mh = lane >> 5;        // m-half (scores)
  const int ts = tw * 32 + (lane & 31);  // this lane's score t
  const int pp = tw * 64 + lane;   // LSTM p-index

  // ---- AGPR tile: XW[b0+bb][ts][mh*128 .. +128) = 64 dwords ----
  XA_DECL(0) XA_DECL(1) XA_DECL(2) XA_DECL(3)
  XA_DECL(4) XA_DECL(5) XA_DECL(6) XA_DECL(7)
  XA_DECL(8) XA_DECL(9) XA_DECL(10) XA_DECL(11)
  XA_DECL(12) XA_DECL(13) XA_DECL(14) XA_DECL(15)
  {
    const unsigned short* p_ =
        XW + (size_t)(b0 + bb) * 32768 + (size_t)ts * 256 + mh * 128;
    XA_LOAD(0) XA_LOAD(1) XA_LOAD(2) XA_LOAD(3)
    XA_LOAD(4) XA_LOAD(5) XA_LOAD(6) XA_LOAD(7)
    XA_LOAD(8) XA_LOAD(9) XA_LOAD(10) XA_LOAD(11)
    XA_LOAD(12) XA_LOAD(13) XA_LOAD(14) XA_LOAD(15)
  }
  // softmax inputs (per lane: t = lane and t = 64+lane of batch bb)
  const float xwl0 = XWl[(size_t)(b0 + bb) * T_SZ + lane];
  const float xwl1 = XWl[(size_t)(b0 + bb) * T_SZ + 64 + lane];

  // init LDS
  for (int i = tid; i < 4 * 520; i += 1024) (&hcbf[0][0])[i] = 0;
  if (tid < 512) {
    int b = tid >> 7, s = tid & 127;
    yL[b][s] = (s < NSTEP) ? Yg[(size_t)(b0 + b) * NSTEP + s] : 0.f;
  }

  // per-lane preloads
  const unsigned vpk = (unsigned)f2bf(v_d[wave * 16 + r]) << 16;  // G1 pack
  float wih4g[4], bs4g[4];
#pragma unroll
  for (int g = 0; g < 4; ++g) { wih4g[g] = W_ih[g * 256 + pp]; bs4g[g] = bsum[g * 256 + pp]; }
  const float wl0 = Wl[0];
  float c_reg = 0.f;  // cell state for (bb, pp)

  // ---- DMA ring: per wave, 24 chunks/step of 2x1KB global_load_lds ----
  // chunk q<8: G1 (W1F tile mt=wave, ks pair 2q,2q+1); q>=8: G2 tile
  // jt=wave*4+((q-8)>>2), ks pair 2*((q-8)&3). Cycles forever.
  const unsigned short* const W1b = W1F + (size_t)wave * 8192 + (size_t)lane * 8;
  const unsigned short* const W2b = W2F + (size_t)wave * 4 * 4096 + (size_t)lane * 8;
  unsigned short* const ringW = &ringS[wave * 3 * 1024];
  int iq = 0, ip = 0;  // issue cursor: chunk-in-step, pane
  auto RISSUE = [&]() {
    const unsigned short* s = (iq < 8) ? (W1b + iq * 1024)
                                       : (W2b + ((iq - 8) >> 2) * 4096 + ((iq - 8) & 3) * 1024);
    unsigned short* d = ringW + ip * 1024;
    __builtin_amdgcn_global_load_lds((const unsigned int*)s, (unsigned int*)d, 16, 0, 0);
    __builtin_amdgcn_global_load_lds((const unsigned int*)(s + 512), (unsigned int*)(d + 512), 16, 0, 0);
    iq = (iq == 23) ? 0 : iq + 1;
    ip = (ip == 2) ? 0 : ip + 1;
  };
  int cp = 0;  // consume pane

  // prologue: 3 chunks in flight
  RISSUE();
  RISSUE();
  RISSUE();

  __syncthreads();  // one-time full barrier

  for (int step = 0; step < NSTEP; ++step) {
    // ---- P1: G1 (dW -> dvL) then G2 (gates -> gL); B from ring, 24 chunks ----
    {
      f32x4 acc = {0.f, 0.f, 0.f, 0.f};
#pragma unroll
      for (int c = 0; c < 8; ++c) {
        RWAIT();
        const unsigned short* pb = ringW + cp * 1024 + lane * 8;
        uint4 bw0 = *(const uint4*)(pb);
        uint4 bw1 = *(const uint4*)(pb + 512);
        uint4 a0 = *(const uint4*)&hcbf[r & 3][(2 * c) * 32 + kg * 8];
        uint4 a1 = *(const uint4*)&hcbf[r & 3][(2 * c + 1) * 32 + kg * 8];
        acc = MFMA_BF16(a0, bw0, acc);
        acc = MFMA_BF16(a1, bw1, acc);
        asm volatile("s_waitcnt lgkmcnt(0)" ::: "memory");  // pane reads done
        __builtin_amdgcn_sched_barrier(0);
        RISSUE();
        cp = (cp == 2) ? 0 : cp + 1;
      }
      if (kg == 0) {
#pragma unroll
        for (int rr = 0; rr < 4; ++rr)
          dvL[rr][wave * 16 + r] = (unsigned)f2bf(acc[rr]) | vpk;
      }
    }
#pragma unroll
    for (int jtl = 0; jtl < 4; ++jtl) {
      f32x4 acc = {0.f, 0.f, 0.f, 0.f};
#pragma unroll
      for (int kp = 0; kp < 4; ++kp) {
        RWAIT();
        const unsigned short* pb = ringW + cp * 1024 + lane * 8;
        uint4 bw0 = *(const uint4*)(pb);
        uint4 bw1 = *(const uint4*)(pb + 512);
        uint4 a0 = *(const uint4*)&hcbf[r & 3][(2 * kp) * 32 + kg * 8];
        uint4 a1 = *(const uint4*)&hcbf[r & 3][(2 * kp + 1) * 32 + kg * 8];
        acc = MFMA_BF16(a0, bw0, acc);
        acc = MFMA_BF16(a1, bw1, acc);
        asm volatile("s_waitcnt lgkmcnt(0)" ::: "memory");
        __builtin_amdgcn_sched_barrier(0);
        RISSUE();
        cp = (cp == 2) ? 0 : cp + 1;
      }
      if (kg == 0) {
#pragma unroll
        for (int rr = 0; rr < 4; ++rr) gL[rr][(wave * 4 + jtl) * 16 + r] = acc[rr];
      }
    }
    BARL();

    // ---- P2: scores, transposed: lane owns t=ts, 128 m from AGPR; dW|v
    //      via broadcast ds_read_b128; single shfl to merge m-halves ----
    {
      const uint4* dvp = (const uint4*)&dvL[bb][mh * 128];
      float s0 = 0.f, s1 = 0.f, s2 = 0.f, s3 = 0.f;
      XA_USE(0) XA_USE(1) XA_USE(2) XA_USE(3)
      XA_USE(4) XA_USE(5) XA_USE(6) XA_USE(7)
      XA_USE(8) XA_USE(9) XA_USE(10) XA_USE(11)
      XA_USE(12) XA_USE(13) XA_USE(14) XA_USE(15)
      float s = (s0 + s1) + (s2 + s3);
      s += __shfl_xor(s, 32, 64);
      if (lane < 32) lL[bb][ts] = s;
    }
    BARL();

    // ---- P3: softmax (redundant, no max-sub) + LSTM, all waves ----
    {
      float l0 = lL[bb][lane], l1 = lL[bb][64 + lane];
      float e0 = fexp2(l0 * 1.4426950408889634f);
      float e1 = fexp2(l1 * 1.4426950408889634f);
      float sm = e0 + e1;
      float yt = e0 * xwl0 + e1 * xwl1;
#pragma unroll
      for (int off = 1; off < 64; off <<= 1) {
        sm += __shfl_xor(sm, off, 64);
        yt += __shfl_xor(yt, off, 64);
      }
      float inv = frcp(sm);
      if (step == NSTEP - 1 && tw == 0) {  // beta only for final ctx
        betaL[bb][lane] = e0 * inv;
        betaL[bb][64 + lane] = e1 * inv;
      }
      yt = yt * inv + wl0 * yL[bb][step];

      float ig = gL[bb][pp] + yt * wih4g[0] + bs4g[0];
      float fg = gL[bb][256 + pp] + yt * wih4g[1] + bs4g[1];
      float gg = gL[bb][512 + pp] + yt * wih4g[2] + bs4g[2];
      float og = gL[bb][768 + pp] + yt * wih4g[3] + bs4g[3];
      float cn = sigm_f(fg) * c_reg + sigm_f(ig) * tanh_f(gg);
      float hn = sigm_f(og) * tanh_f(cn);
      c_reg = cn;
      hcbf[bb][pp] = f2bf(hn);
      hcbf[bb][256 + pp] = f2bf(cn);
    }
    BARL();
  }

  // ---- drain the DMA ring, then reuse pane LDS for ctx ----
  asm volatile("s_waitcnt vmcnt(0)" ::: "memory");
  __syncthreads();
  float* ctxW = (float*)ringS;           // [4][4][256]
  float* ctxL = (float*)ringS + 4096;    // [4][256]

  // ---- ctx partials from final beta (wave (bb,tw) covers 32 t) ----
  {
    const int m4 = lane * 4;
    f32x4 c4 = {0.f, 0.f, 0.f, 0.f};
    for (int t = tw * 32; t < tw * 32 + 32; ++t) {
      float bta = betaL[bb][t];
      f32x4 x4 = *(const f32x4*)&X[(size_t)t * 262144 + (size_t)(b0 + bb) * 256 + m4];
      c4.x += bta * x4.x;
      c4.y += bta * x4.y;
      c4.z += bta * x4.z;
      c4.w += bta * x4.w;
    }
    *(f32x4*)&ctxW[(bb * 4 + tw) * 256 + m4] = c4;
  }
  __syncthreads();

  {
    const int lb2 = tid >> 8, lp2 = tid & 255;
    if (tid < 1024)
      ctxL[lb2 * 256 + lp2] = ctxW[(lb2 * 4 + 0) * 256 + lp2] + ctxW[(lb2 * 4 + 1) * 256 + lp2] +
                              ctxW[(lb2 * 4 + 2) * 256 + lp2] + ctxW[(lb2 * 4 + 3) * 256 + lp2];
  }
  __syncthreads();

  // ---- output head: waves 0..3, batch = wave ----
  if (wave < 4) {
    const int m4 = lane * 4;
    float h0 = 0.f, h1 = 0.f, h2 = 0.f, h3 = 0.f;
    for (int q = 0; q < 512; ++q) {
      float hcq = (q < 256) ? bf2f_lo((unsigned)hcbf[wave][q]) : ctxL[wave * 256 + q - 256];
      const float* wb = Wb_w + (size_t)m4 * 512 + q;
      h0 += hcq * wb[0];
      h1 += hcq * wb[512];
      h2 += hcq * wb[1024];
      h3 += hcq * wb[1536];
    }
    float o = (h0 + Wb_b[m4]) * vb_w[m4] + (h1 + Wb_b[m4 + 1]) * vb_w[m4 + 1] +
              (h2 + Wb_b[m4 + 2]) * vb_w[m4 + 2] + (h3 + Wb_b[m4 + 3]) * vb_w[m4 + 3];
#pragma unroll
    for (int off = 1; off < 64; off <<= 1) o += __shfl_xor(o, off, 64);
    if (lane == 0) outp[b0 + wave] = o + vb_b[0];
  }
}

extern "C" void kernel_launch(void* const* d_in, const int* in_sizes, int n_in,
                              void* d_out, int out_size, void* d_ws, size_t ws_size,
                              hipStream_t stream) {
  const float* Y = (const float*)d_in[0];
  const float* X = (const float*)d_in[1];
  const float* WU_d = (const float*)d_in[2];
  const float* v_d = (const float*)d_in[3];
  const float* Wl = (const float*)d_in[4];
  const float* W_ih = (const float*)d_in[5];
  const float* W_hh = (const float*)d_in[6];
  const float* b_ih = (const float*)d_in[7];
  const float* b_hh = (const float*)d_in[8];
  const float* Wb_w = (const float*)d_in[9];
  const float* Wb_b = (const float*)d_in[10];
  const float* vb_w = (const float*)d_in[11];
  const float* vb_b = (const float*)d_in[12];

  char* ws = (char*)d_ws;
  unsigned short* XW = (unsigned short*)(ws + 0);            // 64 MB
  float* XWl = (float*)(ws + 67108864);                      // 512 KB
  unsigned short* W1F = (unsigned short*)(ws + 67633152);    // 256 KB
  unsigned short* W2F = (unsigned short*)(ws + 67895296);    // 512 KB
  unsigned short* WxF = (unsigned short*)(ws + 68419584);    // 128 KB
  float* bsum = (float*)(ws + 68550656);                     // 4 KB

  prep_w<<<1796, 256, 0, stream>>>(WU_d, W_hh, b_ih, b_hh, W1F, W2F, WxF, bsum);
  prep_xw<<<1024, 256, 0, stream>>>(X, WxF, Wl, XW, XWl);
  scan_k<<<256, 1024, 0, stream>>>(Y, X, XW, XWl, W1F, W2F, bsum, v_d, Wl, W_ih,
                                   Wb_w, Wb_b, vb_w, vb_b, (float*)d_out);
}